// Round 2
// baseline (31.426 us; speedup 1.0000x reference)
//
#include <hip/hip_runtime.h>
#include <hip/hip_bf16.h>

#define IMG_H 384
#define IMG_W 384
#define KSZ 9
#define KR 4              // k//2
#define TILE 16
#define TIN (TILE + 2*KR) // 24
#define SPX 25            // row stride in float4; 25%8==1 -> rows hit distinct bank groups
#define PLANE (IMG_H * IMG_W)

__global__ __launch_bounds__(256) void abf_kernel(
    const float* __restrict__ input,   // [2][3][384][384]
    const float* __restrict__ sigmas,  // [2][2][384][384]
    float* __restrict__ out)           // [2][3][384][384]
{
    __shared__ float4 s_in[TIN * SPX];

    const int b      = blockIdx.z;
    const int tile_x = blockIdx.x * TILE;
    const int tile_y = blockIdx.y * TILE;
    const int tx     = threadIdx.x;   // 0..15
    const int ty     = threadIdx.y;   // 0..15
    const int tid    = ty * TILE + tx;

    // ---- stage 24x24 halo tile, channel-packed (ch0,ch1,ch2,pad) ----
    const float* inb = input + (size_t)b * 3 * PLANE;
    for (int p = tid; p < TIN * TIN; p += 256) {
        int py = p / TIN;
        int px = p - py * TIN;
        int gy = tile_y + py - KR;
        int gx = tile_x + px - KR;
        float4 v = make_float4(0.f, 0.f, 0.f, 0.f);
        if (gy >= 0 && gy < IMG_H && gx >= 0 && gx < IMG_W) {
            int gidx = gy * IMG_W + gx;
            v.x = inb[gidx];
            v.y = inb[PLANE + gidx];
            v.z = inb[2 * PLANE + gidx];
        }
        s_in[py * SPX + px] = v;
    }
    __syncthreads();

    const int ox = tile_x + tx;  // 384 % 16 == 0 -> always in bounds
    const int oy = tile_y + ty;

    const float* sgb = sigmas + (size_t)b * 2 * PLANE;
    const float sg0 = sgb[oy * IMG_W + ox];
    const float sg1 = sgb[PLANE + oy * IMG_W + ox];
    const float sig_s = 1.0f / (fabsf(sg0) + 1e-12f);
    const float sig_r = 1.0f / (fabsf(sg1) + 1e-12f);
    // w = exp2( sc * A + dsq * B ),  sc = (ry^2+rx^2),  dsq = sum_c (v-c)^2
    const float A = -0.5f * 1.44269504f * sig_s * sig_s;
    const float B = -0.5f * 1.44269504f * sig_r * sig_r;

    const float4 cen = s_in[(ty + KR) * SPX + (tx + KR)];

    // center tap: w == 1 exactly
    float wsum = 1.0f;
    float acc0 = cen.x, acc1 = cen.y, acc2 = cen.z;

    #pragma unroll
    for (int dy = 0; dy < KSZ; ++dy) {
        const int base = (ty + dy) * SPX + tx;
        #pragma unroll
        for (int dx = 0; dx < KSZ; ++dx) {
            if (dy == KR && dx == KR) continue;  // center handled above
            const float sc = (float)((dy - KR) * (dy - KR) + (dx - KR) * (dx - KR));
            const float4 v = s_in[base + dx];
            const float d0 = v.x - cen.x;
            const float d1 = v.y - cen.y;
            const float d2 = v.z - cen.z;
            const float dsq = fmaf(d0, d0, fmaf(d1, d1, d2 * d2));
            const float w = __builtin_amdgcn_exp2f(fmaf(dsq, B, sc * A));
            wsum += w;
            acc0 = fmaf(w, v.x, acc0);
            acc1 = fmaf(w, v.y, acc1);
            acc2 = fmaf(w, v.z, acc2);
        }
    }

    const float inv = __builtin_amdgcn_rcpf(wsum);  // wsum >= 1
    float* outb = out + (size_t)b * 3 * PLANE;
    const int oidx = oy * IMG_W + ox;
    outb[oidx]             = acc0 * inv;
    outb[PLANE + oidx]     = acc1 * inv;
    outb[2 * PLANE + oidx] = acc2 * inv;
}

extern "C" void kernel_launch(void* const* d_in, const int* in_sizes, int n_in,
                              void* d_out, int out_size, void* d_ws, size_t ws_size,
                              hipStream_t stream) {
    const float* input  = (const float*)d_in[0];
    const float* sigmas = (const float*)d_in[1];
    float* out = (float*)d_out;

    dim3 block(TILE, TILE, 1);
    dim3 grid(IMG_W / TILE, IMG_H / TILE, 2);
    abf_kernel<<<grid, block, 0, stream>>>(input, sigmas, out);
}

// Round 3
// 19.602 us; speedup vs baseline: 1.6032x; 1.6032x over previous
//
#include <hip/hip_runtime.h>
#include <hip/hip_bf16.h>

#define IMG_H 384
#define IMG_W 384
#define KSZ 9
#define KR 4              // k//2
#define TILE 16
#define TIN (TILE + 2*KR) // 24
#define SPX 25            // row stride in float4 units
#define PLANE (IMG_H * IMG_W)

__global__ __launch_bounds__(256) void abf_kernel(
    const float* __restrict__ input,   // [2][3][384][384]
    const float* __restrict__ sigmas,  // [2][2][384][384]
    float* __restrict__ out)           // [2][3][384][384]
{
    __shared__ float4 s_in[TIN * SPX];

    const int b      = blockIdx.z;
    const int tile_x = blockIdx.x * TILE;
    const int tile_y = blockIdx.y * TILE;
    const int tx     = threadIdx.x;   // 0..15
    const int ty     = threadIdx.y;   // 0..15
    const int tid    = ty * TILE + tx;

    // ---- stage 24x24 halo tile, channel-packed (ch0,ch1,ch2,pad) ----
    const float* inb = input + (size_t)b * 3 * PLANE;
    for (int p = tid; p < TIN * TIN; p += 256) {
        int py = p / TIN;
        int px = p - py * TIN;
        int gy = tile_y + py - KR;
        int gx = tile_x + px - KR;
        float4 v = make_float4(0.f, 0.f, 0.f, 0.f);
        if (gy >= 0 && gy < IMG_H && gx >= 0 && gx < IMG_W) {
            int gidx = gy * IMG_W + gx;
            v.x = inb[gidx];
            v.y = inb[PLANE + gidx];
            v.z = inb[2 * PLANE + gidx];
        }
        s_in[py * SPX + px] = v;
    }
    __syncthreads();

    const int ox = tile_x + tx;
    const int oy = tile_y + ty;

    const float* sgb = sigmas + (size_t)b * 2 * PLANE;
    const float sg0 = sgb[oy * IMG_W + ox];
    const float sg1 = sgb[PLANE + oy * IMG_W + ox];
    const float sig_s = 1.0f / (fabsf(sg0) + 1e-12f);
    const float sig_r = 1.0f / (fabsf(sg1) + 1e-12f);
    // w = exp2( sc * A + dsq * B ),  sc = ry^2 + rx^2,  dsq = sum_c (v_c - cen_c)^2
    const float A = -0.5f * 1.44269504f * sig_s * sig_s;
    const float B = -0.5f * 1.44269504f * sig_r * sig_r;

    const float4 cen = s_in[(ty + KR) * SPX + (tx + KR)];

    float wsum = 0.0f, acc0 = 0.0f, acc1 = 0.0f, acc2 = 0.0f;

    // dy rolled (bounded liveness: <=9 float4 live), dx fully unrolled
    #pragma unroll 1
    for (int dy = 0; dy < KSZ; ++dy) {
        const float ry2 = (float)((dy - KR) * (dy - KR));
        const float syA = ry2 * A;
        const float4* __restrict__ row = &s_in[(ty + dy) * SPX + tx];
        #pragma unroll
        for (int dx = 0; dx < KSZ; ++dx) {
            const float rx2 = (float)((dx - KR) * (dx - KR));
            const float4 v = row[dx];
            const float d0 = v.x - cen.x;
            const float d1 = v.y - cen.y;
            const float d2 = v.z - cen.z;
            const float dsq = fmaf(d0, d0, fmaf(d1, d1, d2 * d2));
            const float scA = fmaf(rx2, A, syA);
            const float w = __builtin_amdgcn_exp2f(fmaf(dsq, B, scA));
            wsum += w;
            acc0 = fmaf(w, v.x, acc0);
            acc1 = fmaf(w, v.y, acc1);
            acc2 = fmaf(w, v.z, acc2);
        }
    }

    const float inv = __builtin_amdgcn_rcpf(wsum);  // wsum >= 1 (center tap w == 1)
    float* outb = out + (size_t)b * 3 * PLANE;
    const int oidx = oy * IMG_W + ox;
    outb[oidx]             = acc0 * inv;
    outb[PLANE + oidx]     = acc1 * inv;
    outb[2 * PLANE + oidx] = acc2 * inv;
}

extern "C" void kernel_launch(void* const* d_in, const int* in_sizes, int n_in,
                              void* d_out, int out_size, void* d_ws, size_t ws_size,
                              hipStream_t stream) {
    const float* input  = (const float*)d_in[0];
    const float* sigmas = (const float*)d_in[1];
    float* out = (float*)d_out;

    dim3 block(TILE, TILE, 1);
    dim3 grid(IMG_W / TILE, IMG_H / TILE, 2);
    abf_kernel<<<grid, block, 0, stream>>>(input, sigmas, out);
}